// Round 5
// baseline (1267.489 us; speedup 1.0000x reference)
//
#include <hip/hip_runtime.h>
#include <math.h>

// ---------------- problem constants ----------------
#define H 256
#define S_STEPS 4
#define B_RXN 512
#define N_MOLS 2048          // B*S
#define ATOMS_PER_MOL 32
#define N_ATOMS 65536        // N_MOLS*32
#define N_BONDS 131072
#define NBP1 131073          // N_BONDS+1
#define MAX_NB 6
#define ATOM_FDIM 133
#define BOND_FDIM 147
#define DEPTH 3
#define N_ITERS 3

typedef unsigned short bf16u;
typedef __attribute__((ext_vector_type(8))) short short8v;  // 8 bf16 = 4 VGPR
typedef __attribute__((ext_vector_type(4))) float f32x4;

__device__ __forceinline__ float b2f(bf16u u) {
    union { unsigned int i; float f; } c; c.i = ((unsigned int)u) << 16; return c.f;
}
__device__ __forceinline__ bf16u f2b(float f) {
    union { float f; unsigned int i; } c; c.f = f;
    unsigned int i = c.i;
    return (bf16u)((i + 0x7FFFu + ((i >> 16) & 1u)) >> 16);   // RNE
}
__device__ __forceinline__ unsigned int diffpack(unsigned int a, unsigned int b) {
    float a0 = b2f((bf16u)(a & 0xFFFFu)), a1 = b2f((bf16u)(a >> 16));
    float b0 = b2f((bf16u)(b & 0xFFFFu)), b1 = b2f((bf16u)(b >> 16));
    return (unsigned int)f2b(a0 - b0) | ((unsigned int)f2b(a1 - b1) << 16);
}

// ============ bond/atom-phase MFMA GEMM, latency-optimized ============
// A fully staged to LDS upfront (all scattered loads in flight); B double-
// buffered from L2-hot WT with ONE barrier per k-step.
// MODE 0 (WI):   A = FB16[M,160] bf16;                         out: INP=acc, MSGA=relu(acc)
// MODE 1 (MSG):  A = amsg[b2a[r]] - msg[b2revb[r]], KP=256;    out: relu(acc+inp), row0=0
// MODE 2 (ATOM): A = [FA16 160 | amsg 256], KP=416, BN=128;    out: f32 relu(acc+bias)
template<int MODE>
__global__ __launch_bounds__(256) void bond_gemm_k(
    const bf16u* __restrict__ A1,   // MODE0: FB16; MODE1: amsg; MODE2: FA16
    const bf16u* __restrict__ A2,   // MODE1: msg;  MODE2: amsg
    const bf16u* __restrict__ inp,  // MODE1 only
    const bf16u* __restrict__ WT,   // [256][KP] bf16
    const float* __restrict__ bias, // MODE2 only
    const int* __restrict__ b2a, const int* __restrict__ b2revb,
    float* __restrict__ outf, bf16u* __restrict__ outb, bf16u* __restrict__ outb2,
    int M)
{
    constexpr int KP  = (MODE == 0) ? 160 : ((MODE == 1) ? 256 : 416);
    constexpr int BN  = (MODE == 2) ? 128 : 256;
    constexpr int NS  = KP / 32;        // k-steps
    constexpr int CPT = KP / 32;        // 16B chunks per thread for A (KP/8/4)
    constexpr int MFN = (MODE == 2) ? 2 : 4;
    constexpr int NBQ = BN / 64;        // uint4 per thread per B step

    __shared__ bf16u As[64][KP + 8];
    __shared__ bf16u Bs[2][BN][40];

    const int tid = threadIdx.x;
    const int lane = tid & 63, w = tid >> 6;
    const int m0 = blockIdx.x * 64;
    const int col0 = (MODE == 2) ? blockIdx.y * BN : 0;
    const int ar = tid >> 2, q = tid & 3;
    const int arow = m0 + ar;
    const bool rok = arow < M;
    const int lr = lane & 15, lk = (lane >> 4) * 8;
    const int WC  = (MODE == 2) ? (w & 1) : w;
    const int WR0 = (MODE == 2) ? (w >> 1) * 32 : 0;

    // ---- issue ALL A loads (scattered for MODE1) ----
    const uint4 z4 = {0u, 0u, 0u, 0u};
    uint4 ua[CPT];
    uint4 ub[(MODE == 1) ? CPT : 1];
    size_t o1 = 0, o2 = 0;
    if (MODE == 1 && rok) {
        o1 = (size_t)b2a[arow] * H;
        o2 = (size_t)b2revb[arow] * H;
    }
    #pragma unroll
    for (int j = 0; j < CPT; ++j) {
        int c = q * CPT + j;
        if (MODE == 0) {
            ua[j] = rok ? *(const uint4*)(A1 + (size_t)arow * 160 + c * 8) : z4;
        } else if (MODE == 1) {
            ua[j] = rok ? *(const uint4*)(A1 + o1 + c * 8) : z4;
            ub[j] = rok ? *(const uint4*)(A2 + o2 + c * 8) : z4;
        } else {
            ua[j] = (c < 20) ? *(const uint4*)(A1 + (size_t)arow * 160 + c * 8)
                             : *(const uint4*)(A2 + (size_t)arow * 256 + (c - 20) * 8);
        }
    }
    // ---- issue B step-0 loads ----
    uint4 bv[NBQ];
    #pragma unroll
    for (int i = 0; i < NBQ; ++i) {
        int id = tid * NBQ + i; int n = id >> 2, kq = id & 3;
        bv[i] = *(const uint4*)(WT + (size_t)(col0 + n) * KP + kq * 8);
    }
    // ---- write A to LDS ----
    #pragma unroll
    for (int j = 0; j < CPT; ++j) {
        int c = q * CPT + j;
        uint4 v = ua[j];
        if (MODE == 1) {
            uint4 u2 = ub[j];
            v.x = diffpack(v.x, u2.x); v.y = diffpack(v.y, u2.y);
            v.z = diffpack(v.z, u2.z); v.w = diffpack(v.w, u2.w);
        }
        *(uint4*)&As[ar][c * 8] = v;
    }
    // ---- write B0 ----
    #pragma unroll
    for (int i = 0; i < NBQ; ++i) {
        int id = tid * NBQ + i; int n = id >> 2, kq = id & 3;
        *(uint4*)&Bs[0][n][kq * 8] = bv[i];
    }
    __syncthreads();

    f32x4 acc[MFN][4];
    const f32x4 zf = {0.f, 0.f, 0.f, 0.f};
    #pragma unroll
    for (int i = 0; i < MFN; ++i)
        #pragma unroll
        for (int j = 0; j < 4; ++j) acc[i][j] = zf;

    // ---- K loop: B dbuf, ONE barrier per step ----
    for (int s = 0; s < NS; ++s) {
        if (s + 1 < NS) {
            #pragma unroll
            for (int i = 0; i < NBQ; ++i) {
                int id = tid * NBQ + i; int n = id >> 2, kq = id & 3;
                bv[i] = *(const uint4*)(WT + (size_t)(col0 + n) * KP + (s + 1) * 32 + kq * 8);
            }
        }
        short8v a[MFN], b[4];
        #pragma unroll
        for (int mf = 0; mf < MFN; ++mf)
            a[mf] = *(const short8v*)&As[WR0 + mf * 16 + lr][s * 32 + lk];
        #pragma unroll
        for (int nf = 0; nf < 4; ++nf)
            b[nf] = *(const short8v*)&Bs[s & 1][WC * 64 + nf * 16 + lr][lk];
        #pragma unroll
        for (int mf = 0; mf < MFN; ++mf)
            #pragma unroll
            for (int nf = 0; nf < 4; ++nf)
                acc[mf][nf] = __builtin_amdgcn_mfma_f32_16x16x32_bf16(
                    a[mf], b[nf], acc[mf][nf], 0, 0, 0);
        if (s + 1 < NS) {
            #pragma unroll
            for (int i = 0; i < NBQ; ++i) {
                int id = tid * NBQ + i; int n = id >> 2, kq = id & 3;
                *(uint4*)&Bs[(s + 1) & 1][n][kq * 8] = bv[i];
            }
            __syncthreads();
        }
    }

    // ---- epilogue ----
    const int rbase = (lane >> 4) * 4;
    #pragma unroll
    for (int mf = 0; mf < MFN; ++mf) {
        #pragma unroll
        for (int nf = 0; nf < 4; ++nf) {
            const int col = col0 + WC * 64 + nf * 16 + lr;
            #pragma unroll
            for (int r = 0; r < 4; ++r) {
                const int row = m0 + WR0 + mf * 16 + rbase + r;
                if (row >= M) continue;
                float v = acc[mf][nf][r];
                const size_t off = (size_t)row * H + col;
                if (MODE == 0) {
                    outb[off] = f2b(v);
                    outb2[off] = f2b(fmaxf(v, 0.f));
                } else if (MODE == 1) {
                    v += b2f(inp[off]);
                    v = fmaxf(v, 0.f);
                    outb[off] = (row == 0) ? (bf16u)0 : f2b(v);
                } else {
                    v += bias[col];
                    outf[off] = fmaxf(v, 0.f);
                }
            }
        }
    }
}

// ================= generic MFMA linear (mid phase) — unchanged =========
template<bool BIAS>
__global__ __launch_bounds__(256) void mfma_lin_k(
    const float* __restrict__ A1, int lda1, int KA1,
    const float* __restrict__ A2, int lda2,
    const bf16u* __restrict__ WT,
    const float* __restrict__ bias,
    float* __restrict__ C, int N, int K)
{
    __shared__ bf16u As[64][40];
    __shared__ bf16u Bs[256][40];
    const int tid = threadIdx.x;
    const int lane = tid & 63, w = tid >> 6;
    const int m0 = blockIdx.x * 64;
    const int col0 = blockIdx.y * 256;
    const int ar = tid >> 2, ac8 = (tid & 3) * 8;
    const int arow = m0 + ar;
    const int lr = lane & 15, lk = (lane >> 4) * 8;

    f32x4 acc[4][4];
    const f32x4 zf = {0.f, 0.f, 0.f, 0.f};
    #pragma unroll
    for (int i = 0; i < 4; ++i)
        #pragma unroll
        for (int j = 0; j < 4; ++j) acc[i][j] = zf;

    for (int k0 = 0; k0 < K; k0 += 32) {
        float v[8];
        #pragma unroll
        for (int j = 0; j < 8; ++j) {
            int kk = k0 + ac8 + j;
            v[j] = (kk < KA1) ? A1[(size_t)arow * lda1 + kk]
                              : A2[(size_t)arow * lda2 + (kk - KA1)];
        }
        ushort4 s0, s1;
        s0.x = f2b(v[0]); s0.y = f2b(v[1]); s0.z = f2b(v[2]); s0.w = f2b(v[3]);
        s1.x = f2b(v[4]); s1.y = f2b(v[5]); s1.z = f2b(v[6]); s1.w = f2b(v[7]);
        *(ushort4*)&As[ar][ac8] = s0;
        *(ushort4*)&As[ar][ac8 + 4] = s1;
        {
            const bf16u* bp = WT + (size_t)(col0 + tid) * K + k0;
            uint4 q0 = *(const uint4*)(bp);
            uint4 q1 = *(const uint4*)(bp + 8);
            uint4 q2 = *(const uint4*)(bp + 16);
            uint4 q3 = *(const uint4*)(bp + 24);
            *(uint4*)&Bs[tid][0]  = q0;
            *(uint4*)&Bs[tid][8]  = q1;
            *(uint4*)&Bs[tid][16] = q2;
            *(uint4*)&Bs[tid][24] = q3;
        }
        __syncthreads();
        short8v a[4], b[4];
        #pragma unroll
        for (int mf = 0; mf < 4; ++mf)
            a[mf] = *(const short8v*)&As[mf * 16 + lr][lk];
        #pragma unroll
        for (int nf = 0; nf < 4; ++nf)
            b[nf] = *(const short8v*)&Bs[w * 64 + nf * 16 + lr][lk];
        #pragma unroll
        for (int mf = 0; mf < 4; ++mf)
            #pragma unroll
            for (int nf = 0; nf < 4; ++nf)
                acc[mf][nf] = __builtin_amdgcn_mfma_f32_16x16x32_bf16(
                    a[mf], b[nf], acc[mf][nf], 0, 0, 0);
        __syncthreads();
    }

    const int rbase = (lane >> 4) * 4;
    #pragma unroll
    for (int mf = 0; mf < 4; ++mf) {
        #pragma unroll
        for (int nf = 0; nf < 4; ++nf) {
            const int col = col0 + w * 64 + nf * 16 + lr;
            #pragma unroll
            for (int r = 0; r < 4; ++r) {
                const int row = m0 + mf * 16 + rbase + r;
                float v = acc[mf][nf][r];
                if (BIAS) v += bias[col];
                C[(size_t)row * N + col] = v;
            }
        }
    }
}

// ---------------- prep kernels ----------------
__global__ __launch_bounds__(256) void prep_wt_k(const float* __restrict__ W,
                                                 bf16u* __restrict__ WT, int K, int KP)
{
    int idx = blockIdx.x * 256 + threadIdx.x;
    if (idx >= 256 * KP) return;
    int n = idx / KP, k = idx - n * KP;
    WT[idx] = (k < K) ? f2b(W[(size_t)k * H + n]) : (bf16u)0;
}

__global__ __launch_bounds__(256) void prep_wto_k(const float* __restrict__ Wo,
                                                  bf16u* __restrict__ WT)
{
    int idx = blockIdx.x * 256 + threadIdx.x;
    if (idx >= 256 * 416) return;
    int n = idx / 416, k = idx - n * 416;
    float v = 0.f;
    if (k < ATOM_FDIM) v = Wo[(size_t)k * H + n];
    else if (k >= 160) v = Wo[(size_t)(ATOM_FDIM + k - 160) * H + n];
    WT[idx] = f2b(v);
}

__global__ __launch_bounds__(256) void prep_wt_t_k(const float* __restrict__ W,
                                                   bf16u* __restrict__ WT, int K)
{
    int idx = blockIdx.x * 256 + threadIdx.x;
    if (idx >= 256 * K) return;
    int n = idx / K, k = idx - n * K;
    WT[idx] = f2b(W[(size_t)k * 256 + n]);
}

__global__ __launch_bounds__(256) void prep_wt_gates_k(const float* __restrict__ Wih,
                                                       const float* __restrict__ Whh,
                                                       bf16u* __restrict__ WT)
{
    int idx = blockIdx.x * 256 + threadIdx.x;
    if (idx >= 1024 * 768) return;
    int n = idx / 768, k = idx - n * 768;
    WT[idx] = f2b(k < 512 ? Wih[(size_t)n * 512 + k] : Whh[(size_t)n * 256 + (k - 512)]);
}

// pack f32 features -> bf16 rows padded to 160
__global__ __launch_bounds__(256) void prep_feat16_k(const float* __restrict__ F,
                                                     bf16u* __restrict__ O,
                                                     int rows, int K)
{
    int idx = blockIdx.x * 256 + threadIdx.x;
    if (idx >= rows * 160) return;
    int r = idx / 160, c = idx - r * 160;
    O[idx] = (c < K) ? f2b(F[(size_t)r * K + c]) : (bf16u)0;
}

// ---------------- small kernels ----------------
__global__ __launch_bounds__(256) void gather6_bf16_k(const bf16u* __restrict__ msg,
                                                      const int* __restrict__ a2b,
                                                      bf16u* __restrict__ outb)
{
    int idx = blockIdx.x * 256 + threadIdx.x;
    if (idx >= N_ATOMS * (H / 8)) return;
    int na = idx >> 5, c = idx & 31;
    const int* nb = a2b + (size_t)na * MAX_NB;
    float s[8] = {0.f, 0.f, 0.f, 0.f, 0.f, 0.f, 0.f, 0.f};
    #pragma unroll
    for (int j = 0; j < MAX_NB; ++j) {
        uint4 u = *(const uint4*)(msg + (size_t)nb[j] * H + c * 8);
        s[0] += b2f((bf16u)(u.x & 0xFFFFu)); s[1] += b2f((bf16u)(u.x >> 16));
        s[2] += b2f((bf16u)(u.y & 0xFFFFu)); s[3] += b2f((bf16u)(u.y >> 16));
        s[4] += b2f((bf16u)(u.z & 0xFFFFu)); s[5] += b2f((bf16u)(u.z >> 16));
        s[6] += b2f((bf16u)(u.w & 0xFFFFu)); s[7] += b2f((bf16u)(u.w >> 16));
    }
    uint4 o;
    o.x = (unsigned int)f2b(s[0]) | ((unsigned int)f2b(s[1]) << 16);
    o.y = (unsigned int)f2b(s[2]) | ((unsigned int)f2b(s[3]) << 16);
    o.z = (unsigned int)f2b(s[4]) | ((unsigned int)f2b(s[5]) << 16);
    o.w = (unsigned int)f2b(s[6]) | ((unsigned int)f2b(s[7]) << 16);
    *(uint4*)(outb + (size_t)na * H + c * 8) = o;
}

__global__ __launch_bounds__(256) void zero_f32_k(float* __restrict__ p, int n)
{
    int idx = blockIdx.x * 256 + threadIdx.x;
    if (idx < n) p[idx] = 0.f;
}

__device__ __forceinline__ float sigm(float x) { return 1.f / (1.f + expf(-x)); }

__global__ __launch_bounds__(256) void lstm_pw_k(const float* __restrict__ gates,
                                                 float* __restrict__ h,
                                                 float* __restrict__ c, int M)
{
    int idx = blockIdx.x * 256 + threadIdx.x;
    if (idx >= M * H) return;
    int m = idx >> 8, d = idx & 255;
    const float* g = gates + (size_t)m * (4 * H);
    float ig = sigm(g[d]);
    float fg = sigm(g[H + d]);
    float gg = tanhf(g[2 * H + d]);
    float og = sigm(g[3 * H + d]);
    float cn = fg * c[idx] + ig * gg;
    c[idx] = cn;
    h[idx] = og * tanhf(cn);
}

__global__ __launch_bounds__(256) void s2s_attn_k(const float* __restrict__ feat,
                                                  const float* __restrict__ h,
                                                  float* __restrict__ q_star, int Nn)
{
    int m = blockIdx.x;
    int t = threadIdx.x;
    int lane = t & 63, wave = t >> 6;
    __shared__ float sc[32];
    const float* f = feat + (size_t)m * Nn * H;
    const float* hm = h + (size_t)m * H;
    for (int n = wave; n < Nn; n += 4) {
        const float* fr = f + (size_t)n * H;
        float p = 0.f;
        #pragma unroll
        for (int u = 0; u < 4; ++u) p += fr[lane * 4 + u] * hm[lane * 4 + u];
        #pragma unroll
        for (int o = 32; o >= 1; o >>= 1) p += __shfl_xor(p, o);
        if (lane == 0) sc[n] = p;
    }
    __syncthreads();
    float mx = -1e30f;
    for (int n = 0; n < Nn; ++n) mx = fmaxf(mx, sc[n]);
    float ssum = 0.f, r = 0.f;
    for (int n = 0; n < Nn; ++n) {
        float a = expf(sc[n] - mx);
        ssum += a;
        r += a * f[(size_t)n * H + t];
    }
    r /= ssum;
    q_star[(size_t)m * (2 * H) + t] = hm[t];
    q_star[(size_t)m * (2 * H) + H + t] = r;
}

__global__ __launch_bounds__(256) void build_x_k(const float* __restrict__ P,
                                                 const float* __restrict__ Q,
                                                 const float* __restrict__ SO,
                                                 const float* __restrict__ b0,
                                                 float* __restrict__ X)
{
    int idx = blockIdx.x * 256 + threadIdx.x;
    if (idx >= B_RXN * S_STEPS * S_STEPS * H) return;
    int d  = idx & 255;
    int s2 = (idx >> 8) & 3;
    int s1 = (idx >> 10) & 3;
    int b  = idx >> 12;
    float v;
    if (s1 == s2) v = SO[((size_t)b * S_STEPS + s1) * H + d];
    else v = P[((size_t)b * S_STEPS + s1) * H + d] + Q[((size_t)b * S_STEPS + s2) * H + d] + b0[d];
    X[idx] = v;
}

// ---------------- launch ----------------
extern "C" void kernel_launch(void* const* d_in, const int* in_sizes, int n_in,
                              void* d_out, int out_size, void* d_ws, size_t ws_size,
                              hipStream_t stream)
{
    const float* f_atoms   = (const float*)d_in[0];
    const float* f_bonds   = (const float*)d_in[1];
    const int*   a2b       = (const int*)d_in[2];
    const int*   b2a       = (const int*)d_in[3];
    const int*   b2revb    = (const int*)d_in[4];
    const float* W_i       = (const float*)d_in[5];
    const float* W_h       = (const float*)d_in[6];
    const float* W_o       = (const float*)d_in[7];
    const float* b_o       = (const float*)d_in[8];
    const float* W_nn0     = (const float*)d_in[9];
    const float* b_nn0     = (const float*)d_in[10];
    const float* W_nn0s    = (const float*)d_in[11];
    const float* b_nn0s    = (const float*)d_in[12];
    const float* W_nn1     = (const float*)d_in[13];
    const float* b_nn1     = (const float*)d_in[14];
    const float* lstm_n_Wih = (const float*)d_in[15];
    const float* lstm_n_Whh = (const float*)d_in[16];
    const float* lstm_n_b   = (const float*)d_in[17];
    const float* node_cond_W = (const float*)d_in[18];
    const float* node_cond_b = (const float*)d_in[19];
    const float* lstm_g_Wih = (const float*)d_in[20];
    const float* lstm_g_Whh = (const float*)d_in[21];
    const float* lstm_g_b   = (const float*)d_in[22];
    const float* graph_cond_W = (const float*)d_in[23];
    const float* graph_cond_b = (const float*)d_in[24];
    float* out = (float*)d_out;

    // ---- workspace layout ----
    const size_t SZB = (size_t)NBP1 * H * sizeof(bf16u);    // 67,109,376 B
    char* base = (char*)d_ws;
    bf16u* INP  = (bf16u*)(base);
    bf16u* MSGA = (bf16u*)(base + SZB);
    bf16u* MSGB = (bf16u*)(base + 2 * SZB);
    bf16u* AMSG = (bf16u*)(base + 3 * SZB);                 // [N_ATOMS,H] bf16
    bf16u* WT_I = (bf16u*)(base + 3 * SZB + 33554432);      // [256][160]
    bf16u* WT_H = (bf16u*)(base + 3 * SZB + 33636352);      // [256][256]
    bf16u* WT_O = (bf16u*)(base + 3 * SZB + 33767424);      // [256][416]
    // packed inputs alias MSGB (dead at time of use)
    bf16u* FB16 = MSGB;                                     // [NBP1][160]  (used before iter0 write)
    bf16u* FA16 = MSGB;                                     // [N_ATOMS][160] (after iter1 GEMM)
    // aliases (regions dead at time of use):
    float* ATOMH = (float*)(base);                          // [N_ATOMS,H] f32, alias INP
    float* SMALL = (float*)(base + SZB);                    // f32 scratch, alias MSGA
    float* GATES  = SMALL;
    float* HN     = SMALL + 2097152;
    float* CN     = SMALL + 2621440;
    float* QSTARN = SMALL + 3145728;
    float* MOL    = SMALL + 4194304;
    float* PP     = SMALL + 4718592;
    float* QQ     = SMALL + 5242880;
    float* SO     = SMALL + 5767168;
    float* XBUF   = SMALL + 6291456;
    float* STEPS  = SMALL + 8388608;
    float* HG     = SMALL + 8912896;
    float* CG     = SMALL + 9043968;
    float* QSTARG = SMALL + 9175040;
    float* GATESG = SMALL + 9437184;
    char* sm2 = base + SZB + 41943040;
    bf16u* WTG_N = (bf16u*)(sm2);
    bf16u* WTG_G = (bf16u*)(sm2 + 1572864);
    bf16u* WT_NC = (bf16u*)(sm2 + 3145728);
    bf16u* WT_P  = (bf16u*)(sm2 + 3407872);
    bf16u* WT_Q  = (bf16u*)(sm2 + 3538944);
    bf16u* WT_S  = (bf16u*)(sm2 + 3670016);
    bf16u* WT_N1 = (bf16u*)(sm2 + 3801088);
    bf16u* WT_GC = (bf16u*)(sm2 + 4325376);

    dim3 blk(256);
    const int MB_BOND = (NBP1 + 63) / 64;     // 2049
    const int MB_ATOM = N_ATOMS / 64;         // 1024

    // 0. weight + input prep
    prep_wt_k<<<(256 * 160 + 255) / 256, blk, 0, stream>>>(W_i, WT_I, BOND_FDIM, 160);
    prep_wt_k<<<(256 * 256 + 255) / 256, blk, 0, stream>>>(W_h, WT_H, H, 256);
    prep_wto_k<<<(256 * 416 + 255) / 256, blk, 0, stream>>>(W_o, WT_O);
    prep_feat16_k<<<((int)((size_t)NBP1 * 160 + 255) / 256), blk, 0, stream>>>(
        f_bonds, FB16, NBP1, BOND_FDIM);

    // 1. inp = FB16 @ W_i -> INP (bf16) ; MSGA = relu(inp) (fused)
    bond_gemm_k<0><<<MB_BOND, blk, 0, stream>>>(
        FB16, nullptr, nullptr, WT_I, nullptr, nullptr, nullptr,
        nullptr, INP, MSGA, NBP1);

    // 2. depth loop (iter0 writes MSGB — FB16 dead by then)
    bf16u* cur = MSGA; bf16u* nxt = MSGB;
    for (int d = 0; d < DEPTH - 1; ++d) {
        gather6_bf16_k<<<(N_ATOMS * (H / 8) + 255) / 256, blk, 0, stream>>>(cur, a2b, AMSG);
        bond_gemm_k<1><<<MB_BOND, blk, 0, stream>>>(
            AMSG, cur, INP, WT_H, nullptr, b2a, b2revb,
            nullptr, nxt, nullptr, NBP1);
        bf16u* t = cur; cur = nxt; nxt = t;
    }

    // 3. nei = gather-sum(final message)  (cur == MSGA)
    gather6_bf16_k<<<(N_ATOMS * (H / 8) + 255) / 256, blk, 0, stream>>>(cur, a2b, AMSG);

    // 3b. packed f_atoms (MSGB dead now) + mid-phase weight prep (MSGA region dead)
    prep_feat16_k<<<((N_ATOMS * 160 + 255) / 256), blk, 0, stream>>>(
        f_atoms, FA16, N_ATOMS, ATOM_FDIM);
    prep_wt_gates_k<<<(1024 * 768 + 255) / 256, blk, 0, stream>>>(lstm_n_Wih, lstm_n_Whh, WTG_N);
    prep_wt_gates_k<<<(1024 * 768 + 255) / 256, blk, 0, stream>>>(lstm_g_Wih, lstm_g_Whh, WTG_G);
    prep_wt_t_k<<<(256 * 512 + 255) / 256, blk, 0, stream>>>(node_cond_W, WT_NC, 512);
    prep_wt_t_k<<<(256 * 256 + 255) / 256, blk, 0, stream>>>(W_nn0, WT_P, 256);
    prep_wt_t_k<<<(256 * 256 + 255) / 256, blk, 0, stream>>>(W_nn0 + 256 * 256, WT_Q, 256);
    prep_wt_t_k<<<(256 * 256 + 255) / 256, blk, 0, stream>>>(W_nn0s, WT_S, 256);
    prep_wt_t_k<<<(256 * 1024 + 255) / 256, blk, 0, stream>>>(W_nn1, WT_N1, 1024);
    prep_wt_t_k<<<(256 * 512 + 255) / 256, blk, 0, stream>>>(graph_cond_W, WT_GC, 512);

    // 4. atom_h = relu([f_atoms, nei] @ W_o + b_o) -> ATOMH f32 (aliases dead INP)
    bond_gemm_k<2><<<dim3(MB_ATOM, 2), blk, 0, stream>>>(
        FA16, AMSG, nullptr, WT_O, b_o, nullptr, nullptr,
        ATOMH, nullptr, nullptr, N_ATOMS);

    // 5. node Set2Set over [2048, 32, 256]
    zero_f32_k<<<(2097152 + 255) / 256, blk, 0, stream>>>(HN, 2097152);  // HN,CN,QSTARN
    for (int it = 0; it < N_ITERS; ++it) {
        mfma_lin_k<true><<<dim3(N_MOLS / 64, 4), blk, 0, stream>>>(
            QSTARN, 2 * H, 2 * H, HN, H, WTG_N, lstm_n_b, GATES, 4 * H, 3 * H);
        lstm_pw_k<<<(N_MOLS * H) / 256, blk, 0, stream>>>(GATES, HN, CN, N_MOLS);
        s2s_attn_k<<<N_MOLS, blk, 0, stream>>>(ATOMH, HN, QSTARN, ATOMS_PER_MOL);
    }
    mfma_lin_k<true><<<dim3(N_MOLS / 64, 1), blk, 0, stream>>>(
        QSTARN, 2 * H, 2 * H, QSTARN, 2 * H, WT_NC, node_cond_b, MOL, H, 2 * H);

    // 6. NN attention over steps
    mfma_lin_k<false><<<dim3(N_MOLS / 64, 1), blk, 0, stream>>>(
        MOL, H, H, MOL, H, WT_P, nullptr, PP, H, H);
    mfma_lin_k<false><<<dim3(N_MOLS / 64, 1), blk, 0, stream>>>(
        MOL, H, H, MOL, H, WT_Q, nullptr, QQ, H, H);
    mfma_lin_k<true><<<dim3(N_MOLS / 64, 1), blk, 0, stream>>>(
        MOL, H, H, MOL, H, WT_S, b_nn0s, SO, H, H);
    build_x_k<<<(B_RXN * 16 * H) / 256, blk, 0, stream>>>(PP, QQ, SO, b_nn0, XBUF);
    mfma_lin_k<true><<<dim3(N_MOLS / 64, 1), blk, 0, stream>>>(
        XBUF, S_STEPS * H, S_STEPS * H, XBUF, S_STEPS * H, WT_N1, b_nn1, STEPS, H, S_STEPS * H);

    // 7. graph Set2Set over [512, 4, 256]
    zero_f32_k<<<(524288 + 255) / 256, blk, 0, stream>>>(HG, 524288);    // HG,CG,QSTARG
    for (int it = 0; it < N_ITERS; ++it) {
        mfma_lin_k<true><<<dim3(B_RXN / 64, 4), blk, 0, stream>>>(
            QSTARG, 2 * H, 2 * H, HG, H, WTG_G, lstm_g_b, GATESG, 4 * H, 3 * H);
        lstm_pw_k<<<(B_RXN * H) / 256, blk, 0, stream>>>(GATESG, HG, CG, B_RXN);
        s2s_attn_k<<<B_RXN, blk, 0, stream>>>(STEPS, HG, QSTARG, S_STEPS);
    }

    // 8. out
    mfma_lin_k<true><<<dim3(B_RXN / 64, 1), blk, 0, stream>>>(
        QSTARG, 2 * H, 2 * H, QSTARG, 2 * H, WT_GC, graph_cond_b, out, H, 2 * H);
}